// Round 1
// baseline (619.932 us; speedup 1.0000x reference)
//
#include <hip/hip_runtime.h>
#include <hip/hip_bf16.h>
#include <math.h>

#define EPSF 1e-8f

// ---------------------------------------------------------------------------
// C = relu(A @ B + bias)   A[M,K] row-major, B[K,N] row-major, C[M,N]
// BM=BN=64, BK=16, 256 threads, 4x4 micro-tile per thread.
// As stored transposed [k][m] with stride 65 (odd -> conflict-light).
// ---------------------------------------------------------------------------
__global__ __launch_bounds__(256) void gemm_bias_relu(
    const float* __restrict__ A, const float* __restrict__ B,
    const float* __restrict__ bias, float* __restrict__ C,
    int M, int K, int N)
{
    __shared__ float As[16][65];   // [k][m]
    __shared__ float Bs[16][64];   // [k][n]
    const int t  = threadIdx.x;
    const int ti = t >> 4, tj = t & 15;
    const int m0 = blockIdx.x * 64;
    const int n0 = blockIdx.y * 64;
    const int arow = t >> 2;          // 0..63
    const int ak   = (t & 3) << 2;    // 0,4,8,12
    const int brow = t >> 4;          // 0..15
    const int bcol = (t & 15) << 2;   // 0..60

    float acc[4][4] = {};

    for (int k0 = 0; k0 < K; k0 += 16) {
        float4 av = make_float4(0.f, 0.f, 0.f, 0.f);
        if (m0 + arow < M)
            av = *(const float4*)(A + (size_t)(m0 + arow) * K + (k0 + ak));
        float4 bv = *(const float4*)(B + (size_t)(k0 + brow) * N + (n0 + bcol));

        __syncthreads();   // protect LDS from readers of previous iteration
        As[ak + 0][arow] = av.x;
        As[ak + 1][arow] = av.y;
        As[ak + 2][arow] = av.z;
        As[ak + 3][arow] = av.w;
        *(float4*)&Bs[brow][bcol] = bv;
        __syncthreads();

        #pragma unroll
        for (int k = 0; k < 16; ++k) {
            float a0 = As[k][ti * 4 + 0];
            float a1 = As[k][ti * 4 + 1];
            float a2 = As[k][ti * 4 + 2];
            float a3 = As[k][ti * 4 + 3];
            float4 b = *(const float4*)&Bs[k][tj * 4];
            acc[0][0] = fmaf(a0, b.x, acc[0][0]);
            acc[0][1] = fmaf(a0, b.y, acc[0][1]);
            acc[0][2] = fmaf(a0, b.z, acc[0][2]);
            acc[0][3] = fmaf(a0, b.w, acc[0][3]);
            acc[1][0] = fmaf(a1, b.x, acc[1][0]);
            acc[1][1] = fmaf(a1, b.y, acc[1][1]);
            acc[1][2] = fmaf(a1, b.z, acc[1][2]);
            acc[1][3] = fmaf(a1, b.w, acc[1][3]);
            acc[2][0] = fmaf(a2, b.x, acc[2][0]);
            acc[2][1] = fmaf(a2, b.y, acc[2][1]);
            acc[2][2] = fmaf(a2, b.z, acc[2][2]);
            acc[2][3] = fmaf(a2, b.w, acc[2][3]);
            acc[3][0] = fmaf(a3, b.x, acc[3][0]);
            acc[3][1] = fmaf(a3, b.y, acc[3][1]);
            acc[3][2] = fmaf(a3, b.z, acc[3][2]);
            acc[3][3] = fmaf(a3, b.w, acc[3][3]);
        }
    }

    const float4 bb = *(const float4*)(bias + n0 + tj * 4);
    #pragma unroll
    for (int r = 0; r < 4; ++r) {
        int gm = m0 + ti * 4 + r;
        if (gm < M) {
            float4 o;
            o.x = fmaxf(acc[r][0] + bb.x, 0.f);
            o.y = fmaxf(acc[r][1] + bb.y, 0.f);
            o.z = fmaxf(acc[r][2] + bb.z, 0.f);
            o.w = fmaxf(acc[r][3] + bb.w, 0.f);
            *(float4*)(C + (size_t)gm * N + n0 + tj * 4) = o;
        }
    }
}

// ---------------------------------------------------------------------------
// Row squared-norms for a [M,128] matrix. One wave (64 lanes) per row.
// ---------------------------------------------------------------------------
__global__ __launch_bounds__(256) void rownorm2(
    const float* __restrict__ X, float* __restrict__ out, int M)
{
    const int wave = threadIdx.x >> 6;
    const int lane = threadIdx.x & 63;
    const int r = blockIdx.x * 4 + wave;
    if (r >= M) return;
    const float2 v = *(const float2*)(X + (size_t)r * 128 + lane * 2);
    float s = v.x * v.x + v.y * v.y;
    #pragma unroll
    for (int off = 32; off > 0; off >>= 1) s += __shfl_down(s, off);
    if (lane == 0) out[r] = s;
}

// ---------------------------------------------------------------------------
// Flash-style pairwise distance + softmax-weighted sum.
// Block: 64 queries (i-tile) x one j-split. No max-tracking needed:
// exponent -dist is in [-inf, 0], sums neither overflow nor underflow.
// ---------------------------------------------------------------------------
__global__ __launch_bounds__(256) void nca_flash(
    const float* __restrict__ h, const float* __restrict__ h2,
    const float* __restrict__ sh, const float* __restrict__ s2,
    const float* __restrict__ y, float* __restrict__ gl, float* __restrict__ gy,
    int N, int jspan)
{
    __shared__ float hT[128][65];   // [k][i]
    __shared__ float sT[128][65];   // [k][j]
    __shared__ float h2s[64], s2s[64], ys[64];
    __shared__ float redL[64], redY[64];

    const int t  = threadIdx.x;
    const int ti = t >> 4, tj = t & 15;
    const int i0 = blockIdx.x * 64;
    const int j0base = blockIdx.y * jspan;
    const int jend   = min(j0base + jspan, N);

    // stage h tile (transposed) once
    #pragma unroll
    for (int it = 0; it < 8; ++it) {
        int f = it * 256 + t;
        int r = f >> 5, q = f & 31;
        float4 v = *(const float4*)(h + (size_t)(i0 + r) * 128 + q * 4);
        hT[q * 4 + 0][r] = v.x;
        hT[q * 4 + 1][r] = v.y;
        hT[q * 4 + 2][r] = v.z;
        hT[q * 4 + 3][r] = v.w;
    }
    if (t < 64) h2s[t] = h2[i0 + t];

    float lacc[4] = {0.f, 0.f, 0.f, 0.f};
    float yacc[4] = {0.f, 0.f, 0.f, 0.f};

    for (int j0 = j0base; j0 < jend; j0 += 64) {
        __syncthreads();   // previous iteration done reading sT
        #pragma unroll
        for (int it = 0; it < 8; ++it) {
            int f = it * 256 + t;
            int r = f >> 5, q = f & 31;
            int j = j0 + r;
            float4 v = make_float4(0.f, 0.f, 0.f, 0.f);
            if (j < jend) v = *(const float4*)(sh + (size_t)j * 128 + q * 4);
            sT[q * 4 + 0][r] = v.x;
            sT[q * 4 + 1][r] = v.y;
            sT[q * 4 + 2][r] = v.z;
            sT[q * 4 + 3][r] = v.w;
        }
        if (t < 64) {
            int j = j0 + t;
            s2s[t] = (j < jend) ? s2[j] : 1e30f;  // OOB -> dist huge -> p = 0
            ys[t]  = (j < jend) ? y[j] : 0.f;
        }
        __syncthreads();

        float dot[4][4] = {};
        #pragma unroll 16
        for (int k = 0; k < 128; ++k) {
            float a0 = hT[k][ti * 4 + 0];
            float a1 = hT[k][ti * 4 + 1];
            float a2 = hT[k][ti * 4 + 2];
            float a3 = hT[k][ti * 4 + 3];
            float b0 = sT[k][tj * 4 + 0];
            float b1 = sT[k][tj * 4 + 1];
            float b2 = sT[k][tj * 4 + 2];
            float b3 = sT[k][tj * 4 + 3];
            dot[0][0] = fmaf(a0, b0, dot[0][0]);
            dot[0][1] = fmaf(a0, b1, dot[0][1]);
            dot[0][2] = fmaf(a0, b2, dot[0][2]);
            dot[0][3] = fmaf(a0, b3, dot[0][3]);
            dot[1][0] = fmaf(a1, b0, dot[1][0]);
            dot[1][1] = fmaf(a1, b1, dot[1][1]);
            dot[1][2] = fmaf(a1, b2, dot[1][2]);
            dot[1][3] = fmaf(a1, b3, dot[1][3]);
            dot[2][0] = fmaf(a2, b0, dot[2][0]);
            dot[2][1] = fmaf(a2, b1, dot[2][1]);
            dot[2][2] = fmaf(a2, b2, dot[2][2]);
            dot[2][3] = fmaf(a2, b3, dot[2][3]);
            dot[3][0] = fmaf(a3, b0, dot[3][0]);
            dot[3][1] = fmaf(a3, b1, dot[3][1]);
            dot[3][2] = fmaf(a3, b2, dot[3][2]);
            dot[3][3] = fmaf(a3, b3, dot[3][3]);
        }

        #pragma unroll
        for (int r = 0; r < 4; ++r) {
            float hv = h2s[ti * 4 + r];
            #pragma unroll
            for (int c = 0; c < 4; ++c) {
                float d2 = hv + s2s[tj * 4 + c] - 2.f * dot[r][c];
                float d  = sqrtf(fmaxf(d2, 0.f) + EPSF);
                float p  = __expf(-d);
                lacc[r] += p;
                yacc[r]  = fmaf(p, ys[tj * 4 + c], yacc[r]);
            }
        }
    }

    // reduce across the 16 threads (tj) sharing each i
    #pragma unroll
    for (int r = 0; r < 4; ++r) {
        #pragma unroll
        for (int off = 8; off > 0; off >>= 1) {
            lacc[r] += __shfl_down(lacc[r], off, 16);
            yacc[r] += __shfl_down(yacc[r], off, 16);
        }
        if (tj == 0) { redL[ti * 4 + r] = lacc[r]; redY[ti * 4 + r] = yacc[r]; }
    }
    __syncthreads();
    if (t < 64) {
        atomicAdd(&gl[i0 + t], redL[t]);
        atomicAdd(&gy[i0 + t], redY[t]);
    }
}

__global__ __launch_bounds__(256) void finalize_div(
    const float* __restrict__ gl, const float* __restrict__ gy,
    float* __restrict__ out, int B)
{
    int i = blockIdx.x * 256 + threadIdx.x;
    if (i < B) out[i] = gy[i] / gl[i];
}

// ---------------------------------------------------------------------------
extern "C" void kernel_launch(void* const* d_in, const int* in_sizes, int n_in,
                              void* d_out, int out_size, void* d_ws, size_t ws_size,
                              hipStream_t stream)
{
    const float* x    = (const float*)d_in[0];  // [1024,256]
    const float* subx = (const float*)d_in[1];  // [30000,256]
    const float* suby = (const float*)d_in[2];  // [30000]
    const float* W1   = (const float*)d_in[3];  // [256,512]
    const float* b1   = (const float*)d_in[4];  // [512]
    const float* W2   = (const float*)d_in[5];  // [512,128]
    const float* b2   = (const float*)d_in[6];  // [128]
    float* out = (float*)d_out;                 // [1024]

    const int B = 1024, N = 30000, D = 256, H1 = 512, H2 = 128;

    char* wsb = (char*)d_ws;
    size_t off = 0;
    auto alloc = [&](size_t bytes) -> float* {
        float* p = (float*)(wsb + off);
        off += (bytes + 255) & ~(size_t)255;
        return p;
    };
    float* z1s = alloc((size_t)N * H1 * sizeof(float));  // 61.44 MB
    float* sh  = alloc((size_t)N * H2 * sizeof(float));  // 15.36 MB
    float* z1x = alloc((size_t)B * H1 * sizeof(float));
    float* h   = alloc((size_t)B * H2 * sizeof(float));
    float* s2  = alloc((size_t)N * sizeof(float));
    float* h2  = alloc((size_t)B * sizeof(float));
    float* gl  = alloc((size_t)B * sizeof(float));
    float* gy  = alloc((size_t)B * sizeof(float));
    (void)ws_size; (void)in_sizes; (void)n_in; (void)out_size;

    dim3 blk(256);
    // MLP: x path
    gemm_bias_relu<<<dim3(B / 64, H1 / 64), blk, 0, stream>>>(x,   W1, b1, z1x, B, D,  H1);
    gemm_bias_relu<<<dim3(B / 64, H2 / 64), blk, 0, stream>>>(z1x, W2, b2, h,   B, H1, H2);
    // MLP: sub_x path
    gemm_bias_relu<<<dim3((N + 63) / 64, H1 / 64), blk, 0, stream>>>(subx, W1, b1, z1s, N, D,  H1);
    gemm_bias_relu<<<dim3((N + 63) / 64, H2 / 64), blk, 0, stream>>>(z1s,  W2, b2, sh,  N, H1, H2);
    // norms
    rownorm2<<<dim3(N / 4), blk, 0, stream>>>(sh, s2, N);
    rownorm2<<<dim3(B / 4), blk, 0, stream>>>(h,  h2, B);
    // accumulators
    hipMemsetAsync(gl, 0, (size_t)B * sizeof(float), stream);
    hipMemsetAsync(gy, 0, (size_t)B * sizeof(float), stream);
    // pairwise + softmax-weighted sum
    const int NSPLIT = 16;
    const int jspan = (N + NSPLIT - 1) / NSPLIT;  // 1875
    nca_flash<<<dim3(B / 64, NSPLIT), blk, 0, stream>>>(h, h2, sh, s2, suby, gl, gy, N, jspan);
    finalize_div<<<dim3(B / 256), blk, 0, stream>>>(gl, gy, out, B);
}

// Round 2
// 350.203 us; speedup vs baseline: 1.7702x; 1.7702x over previous
//
#include <hip/hip_runtime.h>
#include <hip/hip_bf16.h>
#include <math.h>

#define EPSF 1e-8f

typedef __attribute__((ext_vector_type(8))) short bf16x8;
typedef __attribute__((ext_vector_type(4))) float f32x4;

static __device__ inline unsigned short f2bf(float f) {
    __hip_bfloat16 h = __float2bfloat16(f);
    return *reinterpret_cast<unsigned short*>(&h);
}
static __device__ inline float bf2f(unsigned short u) {
    __hip_bfloat16 h;
    *reinterpret_cast<unsigned short*>(&h) = u;
    return __bfloat162float(h);
}

// ---------------------------------------------------------------------------
// C = relu(A @ B + bias)   fp32 VALU GEMM (MLP layers). Unchanged from R1.
// ---------------------------------------------------------------------------
__global__ __launch_bounds__(256) void gemm_bias_relu(
    const float* __restrict__ A, const float* __restrict__ B,
    const float* __restrict__ bias, float* __restrict__ C,
    int M, int K, int N)
{
    __shared__ float As[16][65];   // [k][m]
    __shared__ float Bs[16][64];   // [k][n]
    const int t  = threadIdx.x;
    const int ti = t >> 4, tj = t & 15;
    const int m0 = blockIdx.x * 64;
    const int n0 = blockIdx.y * 64;
    const int arow = t >> 2;
    const int ak   = (t & 3) << 2;
    const int brow = t >> 4;
    const int bcol = (t & 15) << 2;

    float acc[4][4] = {};

    for (int k0 = 0; k0 < K; k0 += 16) {
        float4 av = make_float4(0.f, 0.f, 0.f, 0.f);
        if (m0 + arow < M)
            av = *(const float4*)(A + (size_t)(m0 + arow) * K + (k0 + ak));
        float4 bv = *(const float4*)(B + (size_t)(k0 + brow) * N + (n0 + bcol));

        __syncthreads();
        As[ak + 0][arow] = av.x;
        As[ak + 1][arow] = av.y;
        As[ak + 2][arow] = av.z;
        As[ak + 3][arow] = av.w;
        *(float4*)&Bs[brow][bcol] = bv;
        __syncthreads();

        #pragma unroll
        for (int k = 0; k < 16; ++k) {
            float a0 = As[k][ti * 4 + 0];
            float a1 = As[k][ti * 4 + 1];
            float a2 = As[k][ti * 4 + 2];
            float a3 = As[k][ti * 4 + 3];
            float4 b = *(const float4*)&Bs[k][tj * 4];
            acc[0][0] = fmaf(a0, b.x, acc[0][0]);
            acc[0][1] = fmaf(a0, b.y, acc[0][1]);
            acc[0][2] = fmaf(a0, b.z, acc[0][2]);
            acc[0][3] = fmaf(a0, b.w, acc[0][3]);
            acc[1][0] = fmaf(a1, b.x, acc[1][0]);
            acc[1][1] = fmaf(a1, b.y, acc[1][1]);
            acc[1][2] = fmaf(a1, b.z, acc[1][2]);
            acc[1][3] = fmaf(a1, b.w, acc[1][3]);
            acc[2][0] = fmaf(a2, b.x, acc[2][0]);
            acc[2][1] = fmaf(a2, b.y, acc[2][1]);
            acc[2][2] = fmaf(a2, b.z, acc[2][2]);
            acc[2][3] = fmaf(a2, b.w, acc[2][3]);
            acc[3][0] = fmaf(a3, b.x, acc[3][0]);
            acc[3][1] = fmaf(a3, b.y, acc[3][1]);
            acc[3][2] = fmaf(a3, b.z, acc[3][2]);
            acc[3][3] = fmaf(a3, b.w, acc[3][3]);
        }
    }

    const float4 bb = *(const float4*)(bias + n0 + tj * 4);
    #pragma unroll
    for (int r = 0; r < 4; ++r) {
        int gm = m0 + ti * 4 + r;
        if (gm < M) {
            float4 o;
            o.x = fmaxf(acc[r][0] + bb.x, 0.f);
            o.y = fmaxf(acc[r][1] + bb.y, 0.f);
            o.z = fmaxf(acc[r][2] + bb.z, 0.f);
            o.w = fmaxf(acc[r][3] + bb.w, 0.f);
            *(float4*)(C + (size_t)gm * N + n0 + tj * 4) = o;
        }
    }
}

// ---------------------------------------------------------------------------
// Convert fp32 [M,128] -> bf16 [M,128], and compute squared norm of the
// ROUNDED row (so the GEMM-form distance is exact for the rounded vectors).
// One wave per row.
// ---------------------------------------------------------------------------
__global__ __launch_bounds__(256) void cvt_norm(
    const float* __restrict__ X, unsigned short* __restrict__ Xb,
    float* __restrict__ nrm, int M)
{
    const int wave = threadIdx.x >> 6;
    const int lane = threadIdx.x & 63;
    const int r = blockIdx.x * 4 + wave;
    if (r >= M) return;
    const float2 v = *(const float2*)(X + (size_t)r * 128 + lane * 2);
    unsigned short ux = f2bf(v.x), uy = f2bf(v.y);
    unsigned int packed = ((unsigned int)uy << 16) | ux;
    *(unsigned int*)(Xb + (size_t)r * 128 + lane * 2) = packed;
    float rx = bf2f(ux), ry = bf2f(uy);
    float s = rx * rx + ry * ry;
    #pragma unroll
    for (int off = 32; off > 0; off >>= 1) s += __shfl_down(s, off);
    if (lane == 0) nrm[r] = s;
}

// ---------------------------------------------------------------------------
// Flash NCA with bf16 MFMA for the pairwise dot-products.
// Block: 64-query i-tile x one j-split of jspan. 256 threads = 4 waves;
// wave w owns rows [w*16, w*16+16). Per 64-j chunk each wave computes
// 4 C-tiles of 16x16 via mfma_f32_16x16x32_bf16, K=128 in 4 steps.
// LDS row stride 136 shorts (+16B pad): b128 frag reads hit each bank
// exactly 8x per wave (the b128 minimum) -> no excess conflicts.
// ---------------------------------------------------------------------------
__global__ __launch_bounds__(256) void nca_flash_mfma(
    const unsigned short* __restrict__ hb, const float* __restrict__ h2,
    const unsigned short* __restrict__ shb, const float* __restrict__ s2,
    const float* __restrict__ y, float* __restrict__ gl, float* __restrict__ gy,
    int N, int jspan)
{
    __shared__ __align__(16) unsigned short hA[64 * 136];
    __shared__ __align__(16) unsigned short sB[64 * 136];
    __shared__ float h2s[64], s2s[64], ys[64];

    const int t    = threadIdx.x;
    const int wave = t >> 6;
    const int lane = t & 63;
    const int quad = lane >> 4;
    const int lq   = lane & 15;
    const int i0     = blockIdx.x * 64;
    const int j0base = blockIdx.y * jspan;
    const int jend   = min(j0base + jspan, N);

    // stage h tile (row-major bf16, stride 136)
    #pragma unroll
    for (int it = 0; it < 4; ++it) {
        int flat = it * 256 + t;
        int r = flat >> 4, qc = flat & 15;
        float4 v = *(const float4*)(hb + (size_t)(i0 + r) * 128 + qc * 8);
        *(float4*)&hA[r * 136 + qc * 8] = v;
    }
    if (t < 64) h2s[t] = h2[i0 + t];
    __syncthreads();

    // per-lane invariant: the 4 row-norms this lane's C-regs correspond to
    float myh2[4];
    #pragma unroll
    for (int r = 0; r < 4; ++r) myh2[r] = h2s[wave * 16 + quad * 4 + r];

    float lacc[4] = {0.f, 0.f, 0.f, 0.f};
    float yacc[4] = {0.f, 0.f, 0.f, 0.f};

    for (int j0 = j0base; j0 < jend; j0 += 64) {
        __syncthreads();   // previous iteration done reading sB
        #pragma unroll
        for (int it = 0; it < 4; ++it) {
            int flat = it * 256 + t;
            int r = flat >> 4, qc = flat & 15;
            int j = j0 + r;
            float4 v = make_float4(0.f, 0.f, 0.f, 0.f);
            if (j < jend) v = *(const float4*)(shb + (size_t)j * 128 + qc * 8);
            *(float4*)&sB[r * 136 + qc * 8] = v;
        }
        if (t < 64) {
            int j = j0 + t;
            s2s[t] = (j < jend) ? s2[j] : 1e30f;   // OOB -> dist huge -> p=0
            ys[t]  = (j < jend) ? y[j] : 0.f;
        }
        __syncthreads();

        f32x4 acc[4] = {};
        #pragma unroll
        for (int kk = 0; kk < 4; ++kk) {
            bf16x8 a = *(const bf16x8*)&hA[(wave * 16 + lq) * 136 + kk * 32 + quad * 8];
            #pragma unroll
            for (int jt = 0; jt < 4; ++jt) {
                bf16x8 b = *(const bf16x8*)&sB[(jt * 16 + lq) * 136 + kk * 32 + quad * 8];
                acc[jt] = __builtin_amdgcn_mfma_f32_16x16x32_bf16(a, b, acc[jt], 0, 0, 0);
            }
        }

        #pragma unroll
        for (int jt = 0; jt < 4; ++jt) {
            int col = jt * 16 + lq;
            float ss = s2s[col];
            float sy = ys[col];
            #pragma unroll
            for (int r = 0; r < 4; ++r) {
                float d2 = myh2[r] + ss - 2.f * acc[jt][r];
                float d  = sqrtf(fmaxf(d2, 0.f) + EPSF);
                float p  = __expf(-d);
                lacc[r] += p;
                yacc[r]  = fmaf(p, sy, yacc[r]);
            }
        }
    }

    // reduce across the 16 lanes (lq) of each quad: rows = wave*16+quad*4+r
    #pragma unroll
    for (int r = 0; r < 4; ++r) {
        #pragma unroll
        for (int off = 8; off > 0; off >>= 1) {
            lacc[r] += __shfl_down(lacc[r], off, 16);
            yacc[r] += __shfl_down(yacc[r], off, 16);
        }
    }
    if (lq == 0) {
        int rowl = wave * 16 + quad * 4;
        #pragma unroll
        for (int r = 0; r < 4; ++r) {
            atomicAdd(&gl[i0 + rowl + r], lacc[r]);
            atomicAdd(&gy[i0 + rowl + r], yacc[r]);
        }
    }
}

__global__ __launch_bounds__(256) void finalize_div(
    const float* __restrict__ gl, const float* __restrict__ gy,
    float* __restrict__ out, int B)
{
    int i = blockIdx.x * 256 + threadIdx.x;
    if (i < B) out[i] = gy[i] / gl[i];
}

// ---------------------------------------------------------------------------
extern "C" void kernel_launch(void* const* d_in, const int* in_sizes, int n_in,
                              void* d_out, int out_size, void* d_ws, size_t ws_size,
                              hipStream_t stream)
{
    const float* x    = (const float*)d_in[0];  // [1024,256]
    const float* subx = (const float*)d_in[1];  // [30000,256]
    const float* suby = (const float*)d_in[2];  // [30000]
    const float* W1   = (const float*)d_in[3];  // [256,512]
    const float* b1   = (const float*)d_in[4];  // [512]
    const float* W2   = (const float*)d_in[5];  // [512,128]
    const float* b2   = (const float*)d_in[6];  // [128]
    float* out = (float*)d_out;                 // [1024]

    const int B = 1024, N = 30000, D = 256, H1 = 512, H2 = 128;

    char* wsb = (char*)d_ws;
    size_t off = 0;
    auto alloc = [&](size_t bytes) -> char* {
        char* p = wsb + off;
        off += (bytes + 255) & ~(size_t)255;
        return p;
    };
    float* z1s = (float*)alloc((size_t)N * H1 * sizeof(float));  // 61.44 MB
    float* sh  = (float*)alloc((size_t)N * H2 * sizeof(float));  // 15.36 MB
    float* z1x = (float*)alloc((size_t)B * H1 * sizeof(float));
    float* h   = (float*)alloc((size_t)B * H2 * sizeof(float));
    float* s2  = (float*)alloc((size_t)N * sizeof(float));
    float* h2  = (float*)alloc((size_t)B * sizeof(float));
    float* gl  = (float*)alloc((size_t)B * sizeof(float));
    float* gy  = (float*)alloc((size_t)B * sizeof(float));
    // bf16 copies alias dead fp32 buffers (z1s is dead after GEMM4, z1x after
    // GEMM2) -> footprint unchanged vs R1. Stream-ordered, so safe.
    unsigned short* shb = (unsigned short*)z1s;   // 7.68 MB < 61.44 MB
    unsigned short* hbb = (unsigned short*)z1x;   // 0.26 MB < 2.10 MB
    (void)ws_size; (void)in_sizes; (void)n_in; (void)out_size;

    dim3 blk(256);
    // MLP: x path
    gemm_bias_relu<<<dim3(B / 64, H1 / 64), blk, 0, stream>>>(x,   W1, b1, z1x, B, D,  H1);
    gemm_bias_relu<<<dim3(B / 64, H2 / 64), blk, 0, stream>>>(z1x, W2, b2, h,   B, H1, H2);
    // MLP: sub_x path
    gemm_bias_relu<<<dim3((N + 63) / 64, H1 / 64), blk, 0, stream>>>(subx, W1, b1, z1s, N, D,  H1);
    gemm_bias_relu<<<dim3(N / 64, H2 / 64), blk, 0, stream>>>(z1s,  W2, b2, sh,  N, H1, H2);
    // bf16 conversion + norms of the rounded rows (z1s/z1x now dead -> aliased)
    cvt_norm<<<dim3(N / 4), blk, 0, stream>>>(sh, shb, s2, N);
    cvt_norm<<<dim3(B / 4), blk, 0, stream>>>(h,  hbb, h2, B);
    // accumulators
    hipMemsetAsync(gl, 0, (size_t)B * sizeof(float), stream);
    hipMemsetAsync(gy, 0, (size_t)B * sizeof(float), stream);
    // pairwise + softmax-weighted sum (bf16 MFMA)
    const int JSPAN = 512;
    const int NSPLIT = (N + JSPAN - 1) / JSPAN;  // 59
    nca_flash_mfma<<<dim3(B / 64, NSPLIT), blk, 0, stream>>>(hbb, h2, shb, s2, suby, gl, gy, N, JSPAN);
    finalize_div<<<dim3(B / 256), blk, 0, stream>>>(gl, gy, out, B);
}

// Round 3
// 228.419 us; speedup vs baseline: 2.7140x; 1.5332x over previous
//
#include <hip/hip_runtime.h>
#include <hip/hip_bf16.h>
#include <math.h>

#define EPSF 1e-8f

typedef __attribute__((ext_vector_type(8))) short bf16x8;
typedef __attribute__((ext_vector_type(4))) float f32x4;

static __device__ __forceinline__ unsigned short f2bf(float f) {
    __hip_bfloat16 h = __float2bfloat16(f);
    return *reinterpret_cast<unsigned short*>(&h);
}
static __device__ __forceinline__ float bf2f(unsigned short u) {
    __hip_bfloat16 h;
    *reinterpret_cast<unsigned short*>(&h) = u;
    return __bfloat162float(h);
}

// async global->LDS, 16B per lane. LDS dest is wave-uniform base + lane*16.
static __device__ __forceinline__ void async16(void* lds, const void* g) {
    __builtin_amdgcn_global_load_lds(
        (const __attribute__((address_space(1))) unsigned int*)g,
        (__attribute__((address_space(3))) unsigned int*)lds, 16, 0, 0);
}

// ---------------------------------------------------------------------------
// fp32 -> bf16 hi/lo split, 4 elems per thread. lo = bf16(x - float(hi)).
// ---------------------------------------------------------------------------
__global__ __launch_bounds__(256) void split_bf(
    const float* __restrict__ X, unsigned short* __restrict__ H,
    unsigned short* __restrict__ L, int n4)
{
    int i = blockIdx.x * 256 + threadIdx.x;
    if (i >= n4) return;
    float4 v = ((const float4*)X)[i];
    unsigned short h0 = f2bf(v.x), h1 = f2bf(v.y), h2 = f2bf(v.z), h3 = f2bf(v.w);
    unsigned short l0 = f2bf(v.x - bf2f(h0));
    unsigned short l1 = f2bf(v.y - bf2f(h1));
    unsigned short l2 = f2bf(v.z - bf2f(h2));
    unsigned short l3 = f2bf(v.w - bf2f(h3));
    uint2 hp, lp;
    hp.x = ((unsigned)h1 << 16) | h0;  hp.y = ((unsigned)h3 << 16) | h2;
    lp.x = ((unsigned)l1 << 16) | l0;  lp.y = ((unsigned)l3 << 16) | l2;
    ((uint2*)H)[i] = hp;
    ((uint2*)L)[i] = lp;
}

// ---------------------------------------------------------------------------
// W [K,N] fp32 -> W^T hi/lo bf16 [N,K]. K is a power of two (kshift).
// Tiny matrices (W1: 256x512, W2: 512x128) -> simplicity over coalescing.
// ---------------------------------------------------------------------------
__global__ __launch_bounds__(256) void tsplit(
    const float* __restrict__ W, unsigned short* __restrict__ HT,
    unsigned short* __restrict__ LT, int kshift, int N, int total)
{
    int idx = blockIdx.x * 256 + threadIdx.x;
    if (idx >= total) return;
    int K = 1 << kshift;
    int n = idx >> kshift, k = idx & (K - 1);
    float w = W[(size_t)k * N + n];
    unsigned short h = f2bf(w);
    HT[idx] = h;
    LT[idx] = f2bf(w - bf2f(h));
}

// ---------------------------------------------------------------------------
// Layer-1 GEMM: C = relu((Ah+Al)@(Bh+Bl)^T + bias), 3-term split-bf16 MFMA.
// A planes [M,K] bf16, B planes [N,K] bf16 (pre-transposed weights).
// 128x128 tile, BK=32, 4 waves x (4x4 16x16 tiles), global_load_lds staging.
// Output rounded to single bf16 (z1).
// ---------------------------------------------------------------------------
__global__ __launch_bounds__(256) void gemm_mfma_split3(
    const unsigned short* __restrict__ Ah, const unsigned short* __restrict__ Al,
    const unsigned short* __restrict__ BhT, const unsigned short* __restrict__ BlT,
    const float* __restrict__ bias, unsigned short* __restrict__ Cout,
    int M, int K, int N)
{
    __shared__ __align__(16) unsigned short smem[17408];  // staging 32KB | ctile 128x136
    unsigned short* sAh = smem;
    unsigned short* sAl = smem + 4096;
    unsigned short* sBh = smem + 8192;
    unsigned short* sBl = smem + 12288;

    const int t = threadIdx.x, wave = t >> 6, lane = t & 63;
    const int quad = lane >> 4, lq = lane & 15;
    const int m0 = blockIdx.x * 128, n0 = blockIdx.y * 128;
    const int mhalf = wave >> 1, nhalf = wave & 1;

    // staging geometry: chunk c covers rows c*16..c*16+15; lane -> (row, kcol)
    const int rsub = lane >> 2, kc8 = (lane & 3) * 8;
    const int c0 = wave * 2, c1 = wave * 2 + 1;
    const size_t ra0 = (size_t)min(m0 + c0 * 16 + rsub, M - 1) * K;
    const size_t ra1 = (size_t)min(m0 + c1 * 16 + rsub, M - 1) * K;
    const size_t rb0 = (size_t)(n0 + c0 * 16 + rsub) * K;
    const size_t rb1 = (size_t)(n0 + c1 * 16 + rsub) * K;

    f32x4 acc[4][4];
    #pragma unroll
    for (int i = 0; i < 4; ++i)
        #pragma unroll
        for (int j = 0; j < 4; ++j) acc[i][j] = (f32x4){0.f, 0.f, 0.f, 0.f};

    for (int k0 = 0; k0 < K; k0 += 32) {
        __syncthreads();
        const int g = k0 + kc8;
        async16(sAh + c0 * 512, Ah + ra0 + g);
        async16(sAh + c1 * 512, Ah + ra1 + g);
        async16(sAl + c0 * 512, Al + ra0 + g);
        async16(sAl + c1 * 512, Al + ra1 + g);
        async16(sBh + c0 * 512, BhT + rb0 + g);
        async16(sBh + c1 * 512, BhT + rb1 + g);
        async16(sBl + c0 * 512, BlT + rb0 + g);
        async16(sBl + c1 * 512, BlT + rb1 + g);
        __syncthreads();

        bf16x8 fAh[4], fAl[4], fBh[4], fBl[4];
        #pragma unroll
        for (int i = 0; i < 4; ++i) {
            int arow = mhalf * 64 + i * 16 + lq;
            int brow = nhalf * 64 + i * 16 + lq;
            fAh[i] = *(const bf16x8*)&sAh[arow * 32 + quad * 8];
            fAl[i] = *(const bf16x8*)&sAl[arow * 32 + quad * 8];
            fBh[i] = *(const bf16x8*)&sBh[brow * 32 + quad * 8];
            fBl[i] = *(const bf16x8*)&sBl[brow * 32 + quad * 8];
        }
        #pragma unroll
        for (int mi = 0; mi < 4; ++mi)
            #pragma unroll
            for (int ni = 0; ni < 4; ++ni) {
                acc[mi][ni] = __builtin_amdgcn_mfma_f32_16x16x32_bf16(fAh[mi], fBh[ni], acc[mi][ni], 0, 0, 0);
                acc[mi][ni] = __builtin_amdgcn_mfma_f32_16x16x32_bf16(fAh[mi], fBl[ni], acc[mi][ni], 0, 0, 0);
                acc[mi][ni] = __builtin_amdgcn_mfma_f32_16x16x32_bf16(fAl[mi], fBh[ni], acc[mi][ni], 0, 0, 0);
            }
    }

    // epilogue: bias+relu, round to bf16, repack via LDS for coalesced stores
    __syncthreads();
    unsigned short* ctile = smem;  // 128 x 136
    float bv[4];
    #pragma unroll
    for (int ni = 0; ni < 4; ++ni) bv[ni] = bias[n0 + nhalf * 64 + ni * 16 + lq];
    #pragma unroll
    for (int mi = 0; mi < 4; ++mi)
        #pragma unroll
        for (int ni = 0; ni < 4; ++ni)
            #pragma unroll
            for (int r = 0; r < 4; ++r) {
                float v = fmaxf(acc[mi][ni][r] + bv[ni], 0.f);
                ctile[(mhalf * 64 + mi * 16 + quad * 4 + r) * 136 +
                      (nhalf * 64 + ni * 16 + lq)] = f2bf(v);
            }
    __syncthreads();
    #pragma unroll
    for (int it = 0; it < 8; ++it) {
        int flat = it * 256 + t;
        int row = flat >> 4, seg = flat & 15;
        if (m0 + row < M) {
            bf16x8 v = *(const bf16x8*)&ctile[row * 136 + seg * 8];
            *(bf16x8*)&Cout[(size_t)(m0 + row) * N + n0 + seg * 8] = v;
        }
    }
}

// ---------------------------------------------------------------------------
// Layer-2 GEMM: C = relu(A@(Bh+Bl)^T + bias), A single bf16 plane (z1),
// 2-term split on weights. N == 128 (full width per block) so the epilogue
// also emits the squared row-norm of the ROUNDED bf16 output.
// ---------------------------------------------------------------------------
__global__ __launch_bounds__(256) void gemm_split2_norm(
    const unsigned short* __restrict__ A,
    const unsigned short* __restrict__ BhT, const unsigned short* __restrict__ BlT,
    const float* __restrict__ bias, unsigned short* __restrict__ Cout,
    float* __restrict__ nrm, int M, int K)
{
    __shared__ __align__(16) unsigned short smem[17408];
    unsigned short* sA  = smem;
    unsigned short* sBh = smem + 4096;
    unsigned short* sBl = smem + 8192;

    const int t = threadIdx.x, wave = t >> 6, lane = t & 63;
    const int quad = lane >> 4, lq = lane & 15;
    const int m0 = blockIdx.x * 128;
    const int mhalf = wave >> 1, nhalf = wave & 1;

    const int rsub = lane >> 2, kc8 = (lane & 3) * 8;
    const int c0 = wave * 2, c1 = wave * 2 + 1;
    const size_t ra0 = (size_t)min(m0 + c0 * 16 + rsub, M - 1) * K;
    const size_t ra1 = (size_t)min(m0 + c1 * 16 + rsub, M - 1) * K;
    const size_t rb0 = (size_t)(c0 * 16 + rsub) * K;
    const size_t rb1 = (size_t)(c1 * 16 + rsub) * K;

    f32x4 acc[4][4];
    #pragma unroll
    for (int i = 0; i < 4; ++i)
        #pragma unroll
        for (int j = 0; j < 4; ++j) acc[i][j] = (f32x4){0.f, 0.f, 0.f, 0.f};

    for (int k0 = 0; k0 < K; k0 += 32) {
        __syncthreads();
        const int g = k0 + kc8;
        async16(sA  + c0 * 512, A   + ra0 + g);
        async16(sA  + c1 * 512, A   + ra1 + g);
        async16(sBh + c0 * 512, BhT + rb0 + g);
        async16(sBh + c1 * 512, BhT + rb1 + g);
        async16(sBl + c0 * 512, BlT + rb0 + g);
        async16(sBl + c1 * 512, BlT + rb1 + g);
        __syncthreads();

        bf16x8 fA[4], fBh[4], fBl[4];
        #pragma unroll
        for (int i = 0; i < 4; ++i) {
            int arow = mhalf * 64 + i * 16 + lq;
            int brow = nhalf * 64 + i * 16 + lq;
            fA[i]  = *(const bf16x8*)&sA[arow * 32 + quad * 8];
            fBh[i] = *(const bf16x8*)&sBh[brow * 32 + quad * 8];
            fBl[i] = *(const bf16x8*)&sBl[brow * 32 + quad * 8];
        }
        #pragma unroll
        for (int mi = 0; mi < 4; ++mi)
            #pragma unroll
            for (int ni = 0; ni < 4; ++ni) {
                acc[mi][ni] = __builtin_amdgcn_mfma_f32_16x16x32_bf16(fA[mi], fBh[ni], acc[mi][ni], 0, 0, 0);
                acc[mi][ni] = __builtin_amdgcn_mfma_f32_16x16x32_bf16(fA[mi], fBl[ni], acc[mi][ni], 0, 0, 0);
            }
    }

    __syncthreads();
    unsigned short* ctile = smem;  // 128 x 136
    float bv[4];
    #pragma unroll
    for (int ni = 0; ni < 4; ++ni) bv[ni] = bias[nhalf * 64 + ni * 16 + lq];
    #pragma unroll
    for (int mi = 0; mi < 4; ++mi)
        #pragma unroll
        for (int ni = 0; ni < 4; ++ni)
            #pragma unroll
            for (int r = 0; r < 4; ++r) {
                float v = fmaxf(acc[mi][ni][r] + bv[ni], 0.f);
                ctile[(mhalf * 64 + mi * 16 + quad * 4 + r) * 136 +
                      (nhalf * 64 + ni * 16 + lq)] = f2bf(v);
            }
    __syncthreads();

    // store rounded rows + squared norm of the rounded values
    int row = t >> 1, half = t & 1;
    float s = 0.f;
    if (m0 + row < M) {
        #pragma unroll
        for (int seg = 0; seg < 8; ++seg) {
            bf16x8 v = *(const bf16x8*)&ctile[row * 136 + half * 64 + seg * 8];
            #pragma unroll
            for (int e = 0; e < 8; ++e) {
                float f = bf2f((unsigned short)v[e]);
                s = fmaf(f, f, s);
            }
            *(bf16x8*)&Cout[(size_t)(m0 + row) * 128 + half * 64 + seg * 8] = v;
        }
    }
    s += __shfl_down(s, 1);
    if (half == 0 && m0 + row < M) nrm[m0 + row] = s;
}

// ---------------------------------------------------------------------------
// Flash NCA with bf16 MFMA pairwise dots (unchanged from R2, verified).
// ---------------------------------------------------------------------------
__global__ __launch_bounds__(256) void nca_flash_mfma(
    const unsigned short* __restrict__ hb, const float* __restrict__ h2,
    const unsigned short* __restrict__ shb, const float* __restrict__ s2,
    const float* __restrict__ y, float* __restrict__ gl, float* __restrict__ gy,
    int N, int jspan)
{
    __shared__ __align__(16) unsigned short hA[64 * 136];
    __shared__ __align__(16) unsigned short sB[64 * 136];
    __shared__ float h2s[64], s2s[64], ys[64];

    const int t    = threadIdx.x;
    const int wave = t >> 6;
    const int lane = t & 63;
    const int quad = lane >> 4;
    const int lq   = lane & 15;
    const int i0     = blockIdx.x * 64;
    const int j0base = blockIdx.y * jspan;
    const int jend   = min(j0base + jspan, N);

    #pragma unroll
    for (int it = 0; it < 4; ++it) {
        int flat = it * 256 + t;
        int r = flat >> 4, qc = flat & 15;
        float4 v = *(const float4*)(hb + (size_t)(i0 + r) * 128 + qc * 8);
        *(float4*)&hA[r * 136 + qc * 8] = v;
    }
    if (t < 64) h2s[t] = h2[i0 + t];
    __syncthreads();

    float myh2[4];
    #pragma unroll
    for (int r = 0; r < 4; ++r) myh2[r] = h2s[wave * 16 + quad * 4 + r];

    float lacc[4] = {0.f, 0.f, 0.f, 0.f};
    float yacc[4] = {0.f, 0.f, 0.f, 0.f};

    for (int j0 = j0base; j0 < jend; j0 += 64) {
        __syncthreads();
        #pragma unroll
        for (int it = 0; it < 4; ++it) {
            int flat = it * 256 + t;
            int r = flat >> 4, qc = flat & 15;
            int j = j0 + r;
            float4 v = make_float4(0.f, 0.f, 0.f, 0.f);
            if (j < jend) v = *(const float4*)(shb + (size_t)j * 128 + qc * 8);
            *(float4*)&sB[r * 136 + qc * 8] = v;
        }
        if (t < 64) {
            int j = j0 + t;
            s2s[t] = (j < jend) ? s2[j] : 1e30f;
            ys[t]  = (j < jend) ? y[j] : 0.f;
        }
        __syncthreads();

        f32x4 acc[4];
        #pragma unroll
        for (int jt = 0; jt < 4; ++jt) acc[jt] = (f32x4){0.f, 0.f, 0.f, 0.f};
        #pragma unroll
        for (int kk = 0; kk < 4; ++kk) {
            bf16x8 a = *(const bf16x8*)&hA[(wave * 16 + lq) * 136 + kk * 32 + quad * 8];
            #pragma unroll
            for (int jt = 0; jt < 4; ++jt) {
                bf16x8 b = *(const bf16x8*)&sB[(jt * 16 + lq) * 136 + kk * 32 + quad * 8];
                acc[jt] = __builtin_amdgcn_mfma_f32_16x16x32_bf16(a, b, acc[jt], 0, 0, 0);
            }
        }

        #pragma unroll
        for (int jt = 0; jt < 4; ++jt) {
            int col = jt * 16 + lq;
            float ss = s2s[col];
            float sy = ys[col];
            #pragma unroll
            for (int r = 0; r < 4; ++r) {
                float d2 = myh2[r] + ss - 2.f * acc[jt][r];
                float d  = sqrtf(fmaxf(d2, 0.f) + EPSF);
                float p  = __expf(-d);
                lacc[r] += p;
                yacc[r]  = fmaf(p, sy, yacc[r]);
            }
        }
    }

    #pragma unroll
    for (int r = 0; r < 4; ++r) {
        #pragma unroll
        for (int off = 8; off > 0; off >>= 1) {
            lacc[r] += __shfl_down(lacc[r], off, 16);
            yacc[r] += __shfl_down(yacc[r], off, 16);
        }
    }
    if (lq == 0) {
        int rowl = wave * 16 + quad * 4;
        #pragma unroll
        for (int r = 0; r < 4; ++r) {
            atomicAdd(&gl[i0 + rowl + r], lacc[r]);
            atomicAdd(&gy[i0 + rowl + r], yacc[r]);
        }
    }
}

__global__ __launch_bounds__(256) void finalize_div(
    const float* __restrict__ gl, const float* __restrict__ gy,
    float* __restrict__ out, int B)
{
    int i = blockIdx.x * 256 + threadIdx.x;
    if (i < B) out[i] = gy[i] / gl[i];
}

// ---------------------------------------------------------------------------
extern "C" void kernel_launch(void* const* d_in, const int* in_sizes, int n_in,
                              void* d_out, int out_size, void* d_ws, size_t ws_size,
                              hipStream_t stream)
{
    const float* x    = (const float*)d_in[0];  // [1024,256]
    const float* subx = (const float*)d_in[1];  // [30000,256]
    const float* suby = (const float*)d_in[2];  // [30000]
    const float* W1   = (const float*)d_in[3];  // [256,512]
    const float* b1   = (const float*)d_in[4];  // [512]
    const float* W2   = (const float*)d_in[5];  // [512,128]
    const float* b2   = (const float*)d_in[6];  // [128]
    float* out = (float*)d_out;                 // [1024]

    const int B = 1024, N = 30000, D = 256, H1 = 512, H2 = 128;

    char* wsb = (char*)d_ws;
    size_t off = 0;
    auto alloc = [&](size_t bytes) -> char* {
        char* p = wsb + off;
        off += (bytes + 255) & ~(size_t)255;
        return p;
    };
    unsigned short* sxh  = (unsigned short*)alloc((size_t)N * D * 2);    // 15.36 MB
    unsigned short* sxl  = (unsigned short*)alloc((size_t)N * D * 2);
    unsigned short* xh   = (unsigned short*)alloc((size_t)B * D * 2);
    unsigned short* xl   = (unsigned short*)alloc((size_t)B * D * 2);
    unsigned short* w1hT = (unsigned short*)alloc((size_t)H1 * D * 2);
    unsigned short* w1lT = (unsigned short*)alloc((size_t)H1 * D * 2);
    unsigned short* w2hT = (unsigned short*)alloc((size_t)H2 * H1 * 2);
    unsigned short* w2lT = (unsigned short*)alloc((size_t)H2 * H1 * 2);
    unsigned short* z1s  = (unsigned short*)alloc((size_t)N * H1 * 2);   // 30.72 MB
    unsigned short* z1x  = (unsigned short*)alloc((size_t)B * H1 * 2);
    unsigned short* shb  = (unsigned short*)alloc((size_t)N * H2 * 2);   // 7.68 MB
    unsigned short* hbb  = (unsigned short*)alloc((size_t)B * H2 * 2);
    float* s2 = (float*)alloc((size_t)N * 4);
    float* h2 = (float*)alloc((size_t)B * 4);
    float* gl = (float*)alloc((size_t)B * 4);
    float* gy = (float*)alloc((size_t)B * 4);
    (void)ws_size; (void)in_sizes; (void)n_in; (void)out_size;

    dim3 blk(256);
    // input / weight prep
    split_bf<<<dim3((N * D / 4 + 255) / 256), blk, 0, stream>>>(subx, sxh, sxl, N * D / 4);
    split_bf<<<dim3((B * D / 4 + 255) / 256), blk, 0, stream>>>(x, xh, xl, B * D / 4);
    tsplit<<<dim3((D * H1 + 255) / 256), blk, 0, stream>>>(W1, w1hT, w1lT, 8, H1, D * H1);
    tsplit<<<dim3((H1 * H2 + 255) / 256), blk, 0, stream>>>(W2, w2hT, w2lT, 9, H2, H1 * H2);
    // layer 1 (3-term split)
    gemm_mfma_split3<<<dim3((N + 127) / 128, H1 / 128), blk, 0, stream>>>(
        sxh, sxl, w1hT, w1lT, b1, z1s, N, D, H1);
    gemm_mfma_split3<<<dim3(B / 128, H1 / 128), blk, 0, stream>>>(
        xh, xl, w1hT, w1lT, b1, z1x, B, D, H1);
    // layer 2 (2-term split) + rounded-output row norms
    gemm_split2_norm<<<dim3((N + 127) / 128), blk, 0, stream>>>(
        z1s, w2hT, w2lT, b2, shb, s2, N, H1);
    gemm_split2_norm<<<dim3(B / 128), blk, 0, stream>>>(
        z1x, w2hT, w2lT, b2, hbb, h2, B, H1);
    // accumulators
    hipMemsetAsync(gl, 0, (size_t)B * 4, stream);
    hipMemsetAsync(gy, 0, (size_t)B * 4, stream);
    // pairwise + softmax-weighted sum
    const int JSPAN = 512;
    const int NSPLIT = (N + JSPAN - 1) / JSPAN;  // 59
    nca_flash_mfma<<<dim3(B / 64, NSPLIT), blk, 0, stream>>>(hbb, h2, shb, s2, suby, gl, gy, N, JSPAN);
    finalize_div<<<dim3(B / 256), blk, 0, stream>>>(gl, gy, out, B);
}

// Round 4
// 200.099 us; speedup vs baseline: 3.0981x; 1.1415x over previous
//
#include <hip/hip_runtime.h>
#include <hip/hip_bf16.h>
#include <math.h>

#define EPSF 1e-8f

typedef __attribute__((ext_vector_type(8))) short bf16x8;
typedef __attribute__((ext_vector_type(4))) float f32x4;

static __device__ __forceinline__ unsigned short f2bf(float f) {
    __hip_bfloat16 h = __float2bfloat16(f);
    return *reinterpret_cast<unsigned short*>(&h);
}
static __device__ __forceinline__ float bf2f(unsigned short u) {
    __hip_bfloat16 h;
    *reinterpret_cast<unsigned short*>(&h) = u;
    return __bfloat162float(h);
}

// async global->LDS, 16B/lane. LDS dest = wave-uniform base + lane*16.
// All LDS tiles use chunked layout: 1KB chunk = 16 rows x 32 bf16 cols,
// lane l covers row l>>2, cols (l&3)*8 .. +8  -> frag ds_read_b128 of a
// 16x32 chunk is a contiguous 1KB wave access (conflict-free).
static __device__ __forceinline__ void async16(void* lds, const void* g) {
    __builtin_amdgcn_global_load_lds(
        (const __attribute__((address_space(1))) unsigned int*)g,
        (__attribute__((address_space(3))) unsigned int*)lds, 16, 0, 0);
}

// ---------------------------------------------------------------------------
// Combined hi/lo bf16 split of [subx; x] -> planes [31024,256].
// Also zeroes the gl/gy accumulators (folds away 2 memset launches).
// ---------------------------------------------------------------------------
__global__ __launch_bounds__(256) void split_combined(
    const float* __restrict__ subx, const float* __restrict__ x,
    unsigned short* __restrict__ H, unsigned short* __restrict__ L,
    float* __restrict__ gl, float* __restrict__ gy, int n4, int nsubrow)
{
    int i = blockIdx.x * 256 + threadIdx.x;
    if (i < 512) {
        float4 z = make_float4(0.f, 0.f, 0.f, 0.f);
        if (i < 256) ((float4*)gl)[i] = z;
        else         ((float4*)gy)[i - 256] = z;
    }
    if (i >= n4) return;
    int row = i >> 6;   // 64 float4 per 256-col row
    float4 v = (row < nsubrow)
        ? ((const float4*)subx)[i]
        : ((const float4*)x)[i - (size_t)nsubrow * 64];
    unsigned short h0 = f2bf(v.x), h1 = f2bf(v.y), h2 = f2bf(v.z), h3 = f2bf(v.w);
    unsigned short l0 = f2bf(v.x - bf2f(h0));
    unsigned short l1 = f2bf(v.y - bf2f(h1));
    unsigned short l2 = f2bf(v.z - bf2f(h2));
    unsigned short l3 = f2bf(v.w - bf2f(h3));
    uint2 hp, lp;
    hp.x = ((unsigned)h1 << 16) | h0;  hp.y = ((unsigned)h3 << 16) | h2;
    lp.x = ((unsigned)l1 << 16) | l0;  lp.y = ((unsigned)l3 << 16) | l2;
    ((uint2*)H)[i] = hp;
    ((uint2*)L)[i] = lp;
}

// ---------------------------------------------------------------------------
// W [K,N] fp32 -> W^T hi/lo bf16 [N,K].
// ---------------------------------------------------------------------------
__global__ __launch_bounds__(256) void tsplit(
    const float* __restrict__ W, unsigned short* __restrict__ HT,
    unsigned short* __restrict__ LT, int kshift, int N, int total)
{
    int idx = blockIdx.x * 256 + threadIdx.x;
    if (idx >= total) return;
    int K = 1 << kshift;
    int n = idx >> kshift, k = idx & (K - 1);
    float w = W[(size_t)k * N + n];
    unsigned short h = f2bf(w);
    HT[idx] = h;
    LT[idx] = f2bf(w - bf2f(h));
}

// ---------------------------------------------------------------------------
// Layer-1: C = relu((Ah+Al)@(Bh+Bl)^T + bias), 3-term split-bf16 MFMA.
// 256x128 tile, BK=32 -> 96 MFMA per wave per barrier-pair. K=256, N=512.
// Wave w owns rows w*64..w*64+63, all 128 cols (4 mi x 8 ni 16x16 tiles).
// ---------------------------------------------------------------------------
__global__ __launch_bounds__(256) void gemm_l1(
    const unsigned short* __restrict__ Ah, const unsigned short* __restrict__ Al,
    const unsigned short* __restrict__ BhT, const unsigned short* __restrict__ BlT,
    const float* __restrict__ bias, unsigned short* __restrict__ Cout,
    int M, int K, int N)
{
    __shared__ __align__(16) unsigned short smem[24576];  // 48KB staging; ctile aliases
    unsigned short* sAh = smem;          // 16 chunks (rows 0..255)
    unsigned short* sAl = smem + 8192;
    unsigned short* sBh = smem + 16384;  // 8 chunks (cols/rows 0..127)
    unsigned short* sBl = smem + 20480;

    const int t = threadIdx.x, wave = t >> 6, lane = t & 63;
    const int quad = lane >> 4, lq = lane & 15;
    const int m0 = blockIdx.x * 256, n0 = blockIdx.y * 128;
    const int rsub = lane >> 2, kc8 = (lane & 3) * 8;

    // 48 chunks: 0..15 Ah(rc), 16..31 Al(rc), 32..39 Bh(rc), 40..47 Bl(rc)
    const unsigned short* gp[12];
    unsigned short* lp[12];
    #pragma unroll
    for (int q = 0; q < 12; ++q) {
        int c = wave * 12 + q;
        if (c < 16) {
            gp[q] = Ah + (size_t)min(m0 + c * 16 + rsub, M - 1) * K + kc8;
            lp[q] = sAh + c * 512;
        } else if (c < 32) {
            int rc = c - 16;
            gp[q] = Al + (size_t)min(m0 + rc * 16 + rsub, M - 1) * K + kc8;
            lp[q] = sAl + rc * 512;
        } else if (c < 40) {
            int rc = c - 32;
            gp[q] = BhT + (size_t)(n0 + rc * 16 + rsub) * K + kc8;
            lp[q] = sBh + rc * 512;
        } else {
            int rc = c - 40;
            gp[q] = BlT + (size_t)(n0 + rc * 16 + rsub) * K + kc8;
            lp[q] = sBl + rc * 512;
        }
    }

    f32x4 acc[4][8];
    #pragma unroll
    for (int i = 0; i < 4; ++i)
        #pragma unroll
        for (int j = 0; j < 8; ++j) acc[i][j] = (f32x4){0.f, 0.f, 0.f, 0.f};

    for (int k0 = 0; k0 < K; k0 += 32) {
        __syncthreads();
        #pragma unroll
        for (int q = 0; q < 12; ++q) async16(lp[q], gp[q] + k0);
        __syncthreads();

        #pragma unroll
        for (int nh = 0; nh < 2; ++nh) {
            bf16x8 fBh[4], fBl[4];
            #pragma unroll
            for (int ni = 0; ni < 4; ++ni) {
                int off = (nh * 4 + ni) * 512 + lq * 32 + quad * 8;
                fBh[ni] = *(const bf16x8*)&sBh[off];
                fBl[ni] = *(const bf16x8*)&sBl[off];
            }
            #pragma unroll
            for (int mi = 0; mi < 4; ++mi) {
                int aoff = (wave * 4 + mi) * 512 + lq * 32 + quad * 8;
                bf16x8 fAh = *(const bf16x8*)&sAh[aoff];
                bf16x8 fAl = *(const bf16x8*)&sAl[aoff];
                #pragma unroll
                for (int ni = 0; ni < 4; ++ni) {
                    f32x4 a = acc[mi][nh * 4 + ni];
                    a = __builtin_amdgcn_mfma_f32_16x16x32_bf16(fAh, fBh[ni], a, 0, 0, 0);
                    a = __builtin_amdgcn_mfma_f32_16x16x32_bf16(fAh, fBl[ni], a, 0, 0, 0);
                    a = __builtin_amdgcn_mfma_f32_16x16x32_bf16(fAl, fBh[ni], a, 0, 0, 0);
                    acc[mi][nh * 4 + ni] = a;
                }
            }
        }
    }

    // epilogue: 2 passes of 128 rows through a 128x136 ctile (aliases smem)
    unsigned short* ctile = smem;
    float bv[8];
    #pragma unroll
    for (int ni = 0; ni < 8; ++ni) bv[ni] = bias[n0 + ni * 16 + lq];
    #pragma unroll
    for (int p = 0; p < 2; ++p) {
        __syncthreads();
        if ((wave >> 1) == p) {
            int lrow0 = (wave & 1) * 64;
            #pragma unroll
            for (int mi = 0; mi < 4; ++mi)
                #pragma unroll
                for (int ni = 0; ni < 8; ++ni)
                    #pragma unroll
                    for (int r = 0; r < 4; ++r) {
                        float v = fmaxf(acc[mi][ni][r] + bv[ni], 0.f);
                        ctile[(lrow0 + mi * 16 + quad * 4 + r) * 136 + ni * 16 + lq] = f2bf(v);
                    }
        }
        __syncthreads();
        #pragma unroll
        for (int it = 0; it < 8; ++it) {
            int flat = it * 256 + t;
            int row = flat >> 4, seg = flat & 15;
            int gm = m0 + p * 128 + row;
            if (gm < M) {
                bf16x8 v = *(const bf16x8*)&ctile[row * 136 + seg * 8];
                *(bf16x8*)&Cout[(size_t)gm * N + n0 + seg * 8] = v;
            }
        }
    }
}

// ---------------------------------------------------------------------------
// Layer-2: C = relu(A@(Bh+Bl)^T + bias), 2-term split on weights, N=128.
// 128x128 tile, BK=64 -> 64 MFMA per wave per barrier-pair, 8 drains (K=512).
// Epilogue emits rounded bf16 rows + squared norms of the rounded values.
// ---------------------------------------------------------------------------
__global__ __launch_bounds__(256) void gemm_l2_norm(
    const unsigned short* __restrict__ A,
    const unsigned short* __restrict__ BhT, const unsigned short* __restrict__ BlT,
    const float* __restrict__ bias, unsigned short* __restrict__ Cout,
    float* __restrict__ nrm, int M, int K)
{
    __shared__ __align__(16) unsigned short smem[24576];  // sA|sBh|sBl 16 chunks each
    unsigned short* sBh = smem + 8192;
    unsigned short* sBl = smem + 16384;

    const int t = threadIdx.x, wave = t >> 6, lane = t & 63;
    const int quad = lane >> 4, lq = lane & 15;
    const int m0 = blockIdx.x * 128;
    const int mhalf = wave >> 1, nhalf = wave & 1;
    const int rsub = lane >> 2, kc8 = (lane & 3) * 8;

    // 48 chunks: grp 0 = A, 1 = Bh, 2 = Bl; within grp: (rc = idx>>1, kc = idx&1)
    const unsigned short* gp[12];
    unsigned short* lp[12];
    #pragma unroll
    for (int q = 0; q < 12; ++q) {
        int c = wave * 12 + q;
        int grp = c >> 4, idx = c & 15, rc = idx >> 1, kc = idx & 1;
        const unsigned short* base = grp == 0 ? A : (grp == 1 ? BhT : BlT);
        size_t row = grp == 0 ? (size_t)min(m0 + rc * 16 + rsub, M - 1)
                              : (size_t)(rc * 16 + rsub);
        gp[q] = base + row * K + kc * 32 + kc8;
        lp[q] = smem + grp * 8192 + idx * 512;
    }

    f32x4 acc[4][4];
    #pragma unroll
    for (int i = 0; i < 4; ++i)
        #pragma unroll
        for (int j = 0; j < 4; ++j) acc[i][j] = (f32x4){0.f, 0.f, 0.f, 0.f};

    for (int k0 = 0; k0 < K; k0 += 64) {
        __syncthreads();
        #pragma unroll
        for (int q = 0; q < 12; ++q) async16(lp[q], gp[q] + k0);
        __syncthreads();

        #pragma unroll
        for (int ks = 0; ks < 2; ++ks) {
            bf16x8 fBh[4], fBl[4];
            #pragma unroll
            for (int ni = 0; ni < 4; ++ni) {
                int off = (((nhalf * 4 + ni) * 2) + ks) * 512 + lq * 32 + quad * 8;
                fBh[ni] = *(const bf16x8*)&sBh[off];
                fBl[ni] = *(const bf16x8*)&sBl[off];
            }
            #pragma unroll
            for (int mi = 0; mi < 4; ++mi) {
                bf16x8 fA = *(const bf16x8*)&smem[(((mhalf * 4 + mi) * 2) + ks) * 512 + lq * 32 + quad * 8];
                #pragma unroll
                for (int ni = 0; ni < 4; ++ni) {
                    f32x4 a = acc[mi][ni];
                    a = __builtin_amdgcn_mfma_f32_16x16x32_bf16(fA, fBh[ni], a, 0, 0, 0);
                    a = __builtin_amdgcn_mfma_f32_16x16x32_bf16(fA, fBl[ni], a, 0, 0, 0);
                    acc[mi][ni] = a;
                }
            }
        }
    }

    __syncthreads();
    unsigned short* ctile = smem;  // 128 x 136
    float bv[4];
    #pragma unroll
    for (int ni = 0; ni < 4; ++ni) bv[ni] = bias[nhalf * 64 + ni * 16 + lq];
    #pragma unroll
    for (int mi = 0; mi < 4; ++mi)
        #pragma unroll
        for (int ni = 0; ni < 4; ++ni)
            #pragma unroll
            for (int r = 0; r < 4; ++r) {
                float v = fmaxf(acc[mi][ni][r] + bv[ni], 0.f);
                ctile[(mhalf * 64 + mi * 16 + quad * 4 + r) * 136 +
                      (nhalf * 64 + ni * 16 + lq)] = f2bf(v);
            }
    __syncthreads();

    int row = t >> 1, half = t & 1;
    float s = 0.f;
    if (m0 + row < M) {
        #pragma unroll
        for (int seg = 0; seg < 8; ++seg) {
            bf16x8 v = *(const bf16x8*)&ctile[row * 136 + half * 64 + seg * 8];
            #pragma unroll
            for (int e = 0; e < 8; ++e) {
                float f = bf2f((unsigned short)v[e]);
                s = fmaf(f, f, s);
            }
            *(bf16x8*)&Cout[(size_t)(m0 + row) * 128 + half * 64 + seg * 8] = v;
        }
    }
    s += __shfl_down(s, 1);
    if (half == 0 && m0 + row < M) nrm[m0 + row] = s;
}

// ---------------------------------------------------------------------------
// Flash NCA, bf16 MFMA pairwise dots, async16-staged chunked LDS.
// emb = combined embeddings [31024][128]: rows 0..N-1 = sh, N.. = h.
// ---------------------------------------------------------------------------
__global__ __launch_bounds__(256) void nca_flash_mfma(
    const unsigned short* __restrict__ emb, const float* __restrict__ nrm,
    const float* __restrict__ y, float* __restrict__ gl, float* __restrict__ gy,
    int N, int jspan)
{
    __shared__ __align__(16) unsigned short hA[8192];  // 4 rc x 4 kc chunks
    __shared__ __align__(16) unsigned short sB[8192];
    __shared__ float h2s[64], s2s[64], ys[64];

    const int t = threadIdx.x, wave = t >> 6, lane = t & 63;
    const int quad = lane >> 4, lq = lane & 15;
    const int rsub = lane >> 2, kc8 = (lane & 3) * 8;
    const int i0 = blockIdx.x * 64;
    const int j0base = blockIdx.y * jspan;
    const int jend = min(j0base + jspan, N);
    const unsigned short* hb = emb + (size_t)N * 128;

    // stage h tile: wave w -> rowchunk w, 4 k-chunks
    #pragma unroll
    for (int q = 0; q < 4; ++q)
        async16(hA + (wave * 4 + q) * 512,
                hb + (size_t)(i0 + wave * 16 + rsub) * 128 + q * 32 + kc8);
    if (t < 64) h2s[t] = nrm[N + i0 + t];
    __syncthreads();

    float myh2[4];
    #pragma unroll
    for (int r = 0; r < 4; ++r) myh2[r] = h2s[wave * 16 + quad * 4 + r];

    float lacc[4] = {0.f, 0.f, 0.f, 0.f};
    float yacc[4] = {0.f, 0.f, 0.f, 0.f};

    for (int j0 = j0base; j0 < jend; j0 += 64) {
        __syncthreads();
        int jr = min(j0 + wave * 16 + rsub, jend - 1);
        #pragma unroll
        for (int q = 0; q < 4; ++q)
            async16(sB + (wave * 4 + q) * 512,
                    emb + (size_t)jr * 128 + q * 32 + kc8);
        if (t < 64) {
            int j = j0 + t;
            s2s[t] = (j < jend) ? nrm[j] : 1e30f;
            ys[t]  = (j < jend) ? y[j] : 0.f;
        }
        __syncthreads();

        f32x4 acc[4];
        #pragma unroll
        for (int jt = 0; jt < 4; ++jt) acc[jt] = (f32x4){0.f, 0.f, 0.f, 0.f};
        #pragma unroll
        for (int kk = 0; kk < 4; ++kk) {
            bf16x8 a = *(const bf16x8*)&hA[(wave * 4 + kk) * 512 + lq * 32 + quad * 8];
            #pragma unroll
            for (int jt = 0; jt < 4; ++jt) {
                bf16x8 b = *(const bf16x8*)&sB[(jt * 4 + kk) * 512 + lq * 32 + quad * 8];
                acc[jt] = __builtin_amdgcn_mfma_f32_16x16x32_bf16(a, b, acc[jt], 0, 0, 0);
            }
        }

        #pragma unroll
        for (int jt = 0; jt < 4; ++jt) {
            int col = jt * 16 + lq;
            float ss = s2s[col];
            float sy = ys[col];
            #pragma unroll
            for (int r = 0; r < 4; ++r) {
                float d2 = myh2[r] + ss - 2.f * acc[jt][r];
                float d  = sqrtf(fmaxf(d2, 0.f) + EPSF);
                float p  = __expf(-d);
                lacc[r] += p;
                yacc[r]  = fmaf(p, sy, yacc[r]);
            }
        }
    }

    #pragma unroll
    for (int r = 0; r < 4; ++r) {
        #pragma unroll
        for (int off = 8; off > 0; off >>= 1) {
            lacc[r] += __shfl_down(lacc[r], off, 16);
            yacc[r] += __shfl_down(yacc[r], off, 16);
        }
    }
    if (lq == 0) {
        int rowl = wave * 16 + quad * 4;
        #pragma unroll
        for (int r = 0; r < 4; ++r) {
            atomicAdd(&gl[i0 + rowl + r], lacc[r]);
            atomicAdd(&gy[i0 + rowl + r], yacc[r]);
        }
    }
}

__global__ __launch_bounds__(256) void finalize_div(
    const float* __restrict__ gl, const float* __restrict__ gy,
    float* __restrict__ out, int B)
{
    int i = blockIdx.x * 256 + threadIdx.x;
    if (i < B) out[i] = gy[i] / gl[i];
}

// ---------------------------------------------------------------------------
extern "C" void kernel_launch(void* const* d_in, const int* in_sizes, int n_in,
                              void* d_out, int out_size, void* d_ws, size_t ws_size,
                              hipStream_t stream)
{
    const float* x    = (const float*)d_in[0];  // [1024,256]
    const float* subx = (const float*)d_in[1];  // [30000,256]
    const float* suby = (const float*)d_in[2];  // [30000]
    const float* W1   = (const float*)d_in[3];  // [256,512]
    const float* b1   = (const float*)d_in[4];  // [512]
    const float* W2   = (const float*)d_in[5];  // [512,128]
    const float* b2   = (const float*)d_in[6];  // [128]
    float* out = (float*)d_out;                 // [1024]

    const int B = 1024, N = 30000, D = 256, H1 = 512, H2 = 128;
    const int M = N + B;  // 31024 combined rows

    char* wsb = (char*)d_ws;
    size_t off = 0;
    auto alloc = [&](size_t bytes) -> char* {
        char* p = wsb + off;
        off += (bytes + 255) & ~(size_t)255;
        return p;
    };
    unsigned short* cxh  = (unsigned short*)alloc((size_t)M * D * 2);    // 15.9 MB
    unsigned short* cxl  = (unsigned short*)alloc((size_t)M * D * 2);
    unsigned short* w1hT = (unsigned short*)alloc((size_t)H1 * D * 2);
    unsigned short* w1lT = (unsigned short*)alloc((size_t)H1 * D * 2);
    unsigned short* w2hT = (unsigned short*)alloc((size_t)H2 * H1 * 2);
    unsigned short* w2lT = (unsigned short*)alloc((size_t)H2 * H1 * 2);
    unsigned short* z1   = (unsigned short*)alloc((size_t)M * H1 * 2);   // 31.8 MB
    unsigned short* emb  = (unsigned short*)alloc((size_t)M * H2 * 2);   // 7.9 MB
    float* nrm = (float*)alloc((size_t)M * 4);
    float* gl  = (float*)alloc((size_t)B * 4);
    float* gy  = (float*)alloc((size_t)B * 4);
    (void)ws_size; (void)in_sizes; (void)n_in; (void)out_size;

    dim3 blk(256);
    // prep: combined split (+ gl/gy zeroing), weight transpose-splits
    split_combined<<<dim3(M * D / 4 / 256), blk, 0, stream>>>(
        subx, x, cxh, cxl, gl, gy, M * D / 4, N);
    tsplit<<<dim3(D * H1 / 256), blk, 0, stream>>>(W1, w1hT, w1lT, 8, H1, D * H1);
    tsplit<<<dim3(H1 * H2 / 256), blk, 0, stream>>>(W2, w2hT, w2lT, 9, H2, H1 * H2);
    // layer 1 (3-term), combined M
    gemm_l1<<<dim3((M + 255) / 256, H1 / 128), blk, 0, stream>>>(
        cxh, cxl, w1hT, w1lT, b1, z1, M, D, H1);
    // layer 2 (2-term) + rounded-row norms, combined M
    gemm_l2_norm<<<dim3((M + 127) / 128), blk, 0, stream>>>(
        z1, w2hT, w2lT, b2, emb, nrm, M, H1);
    // pairwise + softmax-weighted sum
    const int JSPAN = 512;
    const int NSPLIT = (N + JSPAN - 1) / JSPAN;  // 59
    nca_flash_mfma<<<dim3(B / 64, NSPLIT), blk, 0, stream>>>(
        emb, nrm, suby, gl, gy, N, JSPAN);
    finalize_div<<<dim3(B / 256), blk, 0, stream>>>(gl, gy, out, B);
}

// Round 5
// 193.268 us; speedup vs baseline: 3.2076x; 1.0353x over previous
//
#include <hip/hip_runtime.h>
#include <hip/hip_bf16.h>
#include <math.h>

#define EPSF 1e-8f

typedef __attribute__((ext_vector_type(8))) short bf16x8;
typedef __attribute__((ext_vector_type(4))) float f32x4;

static __device__ __forceinline__ unsigned short f2bf(float f) {
    __hip_bfloat16 h = __float2bfloat16(f);
    return *reinterpret_cast<unsigned short*>(&h);
}
static __device__ __forceinline__ float bf2f(unsigned short u) {
    __hip_bfloat16 h;
    *reinterpret_cast<unsigned short*>(&h) = u;
    return __bfloat162float(h);
}

// async global->LDS, 16B/lane. LDS dest = wave-uniform base + lane*16.
// Chunked layout: 1KB chunk = 16 rows x 32 bf16; lane l covers row l>>2,
// cols (l&3)*8..+8. Frag ds_read_b128 of a chunk = contiguous 1KB (no conflict).
static __device__ __forceinline__ void async16(void* lds, const void* g) {
    __builtin_amdgcn_global_load_lds(
        (const __attribute__((address_space(1))) unsigned int*)g,
        (__attribute__((address_space(3))) unsigned int*)lds, 16, 0, 0);
}

// ---------------------------------------------------------------------------
// Combined hi/lo bf16 split of [subx; x] -> planes [31024,256].
// Also zeroes the gl/gy accumulators.
// ---------------------------------------------------------------------------
__global__ __launch_bounds__(256) void split_combined(
    const float* __restrict__ subx, const float* __restrict__ x,
    unsigned short* __restrict__ H, unsigned short* __restrict__ L,
    float* __restrict__ gl, float* __restrict__ gy, int n4, int nsubrow)
{
    int i = blockIdx.x * 256 + threadIdx.x;
    if (i < 512) {
        float4 z = make_float4(0.f, 0.f, 0.f, 0.f);
        if (i < 256) ((float4*)gl)[i] = z;
        else         ((float4*)gy)[i - 256] = z;
    }
    if (i >= n4) return;
    int row = i >> 6;   // 64 float4 per 256-col row
    float4 v = (row < nsubrow)
        ? ((const float4*)subx)[i]
        : ((const float4*)x)[i - (size_t)nsubrow * 64];
    unsigned short h0 = f2bf(v.x), h1 = f2bf(v.y), h2 = f2bf(v.z), h3 = f2bf(v.w);
    unsigned short l0 = f2bf(v.x - bf2f(h0));
    unsigned short l1 = f2bf(v.y - bf2f(h1));
    unsigned short l2 = f2bf(v.z - bf2f(h2));
    unsigned short l3 = f2bf(v.w - bf2f(h3));
    uint2 hp, lp;
    hp.x = ((unsigned)h1 << 16) | h0;  hp.y = ((unsigned)h3 << 16) | h2;
    lp.x = ((unsigned)l1 << 16) | l0;  lp.y = ((unsigned)l3 << 16) | l2;
    ((uint2*)H)[i] = hp;
    ((uint2*)L)[i] = lp;
}

// ---------------------------------------------------------------------------
// W [K,N] fp32 -> W^T hi/lo bf16 [N,K].
// ---------------------------------------------------------------------------
__global__ __launch_bounds__(256) void tsplit(
    const float* __restrict__ W, unsigned short* __restrict__ HT,
    unsigned short* __restrict__ LT, int kshift, int N, int total)
{
    int idx = blockIdx.x * 256 + threadIdx.x;
    if (idx >= total) return;
    int K = 1 << kshift;
    int n = idx >> kshift, k = idx & (K - 1);
    float w = W[(size_t)k * N + n];
    unsigned short h = f2bf(w);
    HT[idx] = h;
    LT[idx] = f2bf(w - bf2f(h));
}

// ---------------------------------------------------------------------------
// Layer-1: C = relu((Ah+Al)@(Bh+Bl)^T + bias), 3-term split-bf16 MFMA.
// 128x128 tile, BK=32. A-frags loaded DIRECTLY from global (16B/lane
// contiguous; A rows block-private, L2/L3-resident). Only weights staged
// in LDS (16KB/iter). LDS 34KB (ctile alias) -> 4 blocks/CU by LDS.
// XCD swizzle: contiguous newbid range per XCD; the 4 n-tiles of each
// m-tile stay inside one XCD -> A fetched once per XCD-L2.
// ---------------------------------------------------------------------------
__global__ __launch_bounds__(256) void gemm_l1(
    const unsigned short* __restrict__ Ah, const unsigned short* __restrict__ Al,
    const unsigned short* __restrict__ BhT, const unsigned short* __restrict__ BlT,
    const float* __restrict__ bias, unsigned short* __restrict__ Cout,
    int M, int K, int N)
{
    __shared__ __align__(16) unsigned short smem[17408];  // B stage 16KB | ctile 128x136
    unsigned short* sBh = smem;          // 8 chunks
    unsigned short* sBl = smem + 4096;   // 8 chunks

    // inverse round-robin: XCD k owns a contiguous newbid range
    const int nb = gridDim.x;
    const int per = nb >> 3, rem = nb & 7;
    const int xcd = blockIdx.x & 7, slot = blockIdx.x >> 3;
    const int newbid = xcd * per + min(xcd, rem) + slot;
    const int m0 = (newbid >> 2) * 128, n0 = (newbid & 3) * 128;

    const int t = threadIdx.x, wave = t >> 6, lane = t & 63;
    const int quad = lane >> 4, lq = lane & 15;
    const int mhalf = wave >> 1, nhalf = wave & 1;
    const int rsub = lane >> 2, kc8 = (lane & 3) * 8;

    // B staging: 16 chunks (8 Bh + 8 Bl), 4 per wave
    const unsigned short* gb[4];
    unsigned short* lb[4];
    #pragma unroll
    for (int q = 0; q < 4; ++q) {
        int c = wave * 4 + q;
        int plane = c >> 3, rc = c & 7;
        gb[q] = (plane ? BlT : BhT) + (size_t)(n0 + rc * 16 + rsub) * K + kc8;
        lb[q] = (plane ? sBl : sBh) + rc * 512;
    }
    // A fragment row bases (direct global frags)
    const unsigned short* pAh[4];
    const unsigned short* pAl[4];
    #pragma unroll
    for (int mi = 0; mi < 4; ++mi) {
        size_t r = (size_t)min(m0 + mhalf * 64 + mi * 16 + lq, M - 1) * K + quad * 8;
        pAh[mi] = Ah + r;
        pAl[mi] = Al + r;
    }

    f32x4 acc[4][4];
    #pragma unroll
    for (int i = 0; i < 4; ++i)
        #pragma unroll
        for (int j = 0; j < 4; ++j) acc[i][j] = (f32x4){0.f, 0.f, 0.f, 0.f};

    for (int k0 = 0; k0 < K; k0 += 32) {
        __syncthreads();   // prev iter done reading sB
        #pragma unroll
        for (int q = 0; q < 4; ++q) async16(lb[q], gb[q] + k0);
        // A-frag loads issued here: overlap the B-drain
        bf16x8 fAh[4], fAl[4];
        #pragma unroll
        for (int mi = 0; mi < 4; ++mi) {
            fAh[mi] = *(const bf16x8*)(pAh[mi] + k0);
            fAl[mi] = *(const bf16x8*)(pAl[mi] + k0);
        }
        __syncthreads();   // B staged

        #pragma unroll
        for (int ni = 0; ni < 4; ++ni) {
            int off = (nhalf * 4 + ni) * 512 + lq * 32 + quad * 8;
            bf16x8 fBh = *(const bf16x8*)&sBh[off];
            bf16x8 fBl = *(const bf16x8*)&sBl[off];
            #pragma unroll
            for (int mi = 0; mi < 4; ++mi) {
                f32x4 a = acc[mi][ni];
                a = __builtin_amdgcn_mfma_f32_16x16x32_bf16(fAh[mi], fBh, a, 0, 0, 0);
                a = __builtin_amdgcn_mfma_f32_16x16x32_bf16(fAh[mi], fBl, a, 0, 0, 0);
                a = __builtin_amdgcn_mfma_f32_16x16x32_bf16(fAl[mi], fBh, a, 0, 0, 0);
                acc[mi][ni] = a;
            }
        }
    }

    // epilogue: bias+relu, round to bf16, repack via LDS for coalesced stores
    __syncthreads();
    unsigned short* ctile = smem;  // 128 x 136
    float bv[4];
    #pragma unroll
    for (int ni = 0; ni < 4; ++ni) bv[ni] = bias[n0 + nhalf * 64 + ni * 16 + lq];
    #pragma unroll
    for (int mi = 0; mi < 4; ++mi)
        #pragma unroll
        for (int ni = 0; ni < 4; ++ni)
            #pragma unroll
            for (int r = 0; r < 4; ++r) {
                float v = fmaxf(acc[mi][ni][r] + bv[ni], 0.f);
                ctile[(mhalf * 64 + mi * 16 + quad * 4 + r) * 136 +
                      (nhalf * 64 + ni * 16 + lq)] = f2bf(v);
            }
    __syncthreads();
    #pragma unroll
    for (int it = 0; it < 8; ++it) {
        int flat = it * 256 + t;
        int row = flat >> 4, seg = flat & 15;
        if (m0 + row < M) {
            bf16x8 v = *(const bf16x8*)&ctile[row * 136 + seg * 8];
            *(bf16x8*)&Cout[(size_t)(m0 + row) * N + n0 + seg * 8] = v;
        }
    }
}

// ---------------------------------------------------------------------------
// Layer-2: C = relu(A@(Bh+Bl)^T + bias), 2-term split on weights, N=128.
// 128x128 tile, BK=64 (2 kk-steps/iter, 8 iters). A (z1) frags direct from
// global; only W2^T hi+lo staged (32KB/iter). Epilogue: rounded bf16 rows +
// squared norms of the rounded values.
// ---------------------------------------------------------------------------
__global__ __launch_bounds__(256) void gemm_l2_norm(
    const unsigned short* __restrict__ A,
    const unsigned short* __restrict__ BhT, const unsigned short* __restrict__ BlT,
    const float* __restrict__ bias, unsigned short* __restrict__ Cout,
    float* __restrict__ nrm, int M, int K)
{
    __shared__ __align__(16) unsigned short smem[17408];  // stage 32KB? no: 16384 | ctile
    unsigned short* sBh = smem;          // 16 chunks (8 rc x 2 kc)
    unsigned short* sBl = smem + 8192;   // 16 chunks

    const int t = threadIdx.x, wave = t >> 6, lane = t & 63;
    const int quad = lane >> 4, lq = lane & 15;
    const int m0 = blockIdx.x * 128;
    const int mhalf = wave >> 1, nhalf = wave & 1;
    const int rsub = lane >> 2, kc8 = (lane & 3) * 8;

    // W2 staging: 32 chunks (plane, rc 0..7, kc 0..1), 8 per wave
    const unsigned short* gb[8];
    unsigned short* lb[8];
    #pragma unroll
    for (int q = 0; q < 8; ++q) {
        int c = wave * 8 + q;            // 0..31
        int plane = c >> 4, idx = c & 15, rc = idx >> 1, kc = idx & 1;
        gb[q] = (plane ? BlT : BhT) + (size_t)(rc * 16 + rsub) * K + kc * 32 + kc8;
        lb[q] = (plane ? sBl : sBh) + idx * 512;
    }
    const unsigned short* pA[4];
    #pragma unroll
    for (int mi = 0; mi < 4; ++mi)
        pA[mi] = A + (size_t)min(m0 + mhalf * 64 + mi * 16 + lq, M - 1) * K + quad * 8;

    f32x4 acc[4][4];
    #pragma unroll
    for (int i = 0; i < 4; ++i)
        #pragma unroll
        for (int j = 0; j < 4; ++j) acc[i][j] = (f32x4){0.f, 0.f, 0.f, 0.f};

    for (int k0 = 0; k0 < K; k0 += 64) {
        __syncthreads();
        #pragma unroll
        for (int q = 0; q < 8; ++q) async16(lb[q], gb[q] + k0);
        bf16x8 fA[4][2];
        #pragma unroll
        for (int mi = 0; mi < 4; ++mi)
            #pragma unroll
            for (int ks = 0; ks < 2; ++ks)
                fA[mi][ks] = *(const bf16x8*)(pA[mi] + k0 + ks * 32);
        __syncthreads();

        #pragma unroll
        for (int ks = 0; ks < 2; ++ks) {
            #pragma unroll
            for (int ni = 0; ni < 4; ++ni) {
                int off = ((nhalf * 4 + ni) * 2 + ks) * 512 + lq * 32 + quad * 8;
                bf16x8 fBh = *(const bf16x8*)&sBh[off];
                bf16x8 fBl = *(const bf16x8*)&sBl[off];
                #pragma unroll
                for (int mi = 0; mi < 4; ++mi) {
                    f32x4 a = acc[mi][ni];
                    a = __builtin_amdgcn_mfma_f32_16x16x32_bf16(fA[mi][ks], fBh, a, 0, 0, 0);
                    a = __builtin_amdgcn_mfma_f32_16x16x32_bf16(fA[mi][ks], fBl, a, 0, 0, 0);
                    acc[mi][ni] = a;
                }
            }
        }
    }

    __syncthreads();
    unsigned short* ctile = smem;  // 128 x 136
    float bv[4];
    #pragma unroll
    for (int ni = 0; ni < 4; ++ni) bv[ni] = bias[nhalf * 64 + ni * 16 + lq];
    #pragma unroll
    for (int mi = 0; mi < 4; ++mi)
        #pragma unroll
        for (int ni = 0; ni < 4; ++ni)
            #pragma unroll
            for (int r = 0; r < 4; ++r) {
                float v = fmaxf(acc[mi][ni][r] + bv[ni], 0.f);
                ctile[(mhalf * 64 + mi * 16 + quad * 4 + r) * 136 +
                      (nhalf * 64 + ni * 16 + lq)] = f2bf(v);
            }
    __syncthreads();

    int row = t >> 1, half = t & 1;
    float s = 0.f;
    if (m0 + row < M) {
        #pragma unroll
        for (int seg = 0; seg < 8; ++seg) {
            bf16x8 v = *(const bf16x8*)&ctile[row * 136 + half * 64 + seg * 8];
            #pragma unroll
            for (int e = 0; e < 8; ++e) {
                float f = bf2f((unsigned short)v[e]);
                s = fmaf(f, f, s);
            }
            *(bf16x8*)&Cout[(size_t)(m0 + row) * 128 + half * 64 + seg * 8] = v;
        }
    }
    s += __shfl_down(s, 1);
    if (half == 0 && m0 + row < M) nrm[m0 + row] = s;
}

// ---------------------------------------------------------------------------
// Flash NCA, bf16 MFMA pairwise dots, async16-staged chunked LDS.
// emb = combined embeddings [31024][128]: rows 0..N-1 = sh, N.. = h.
// ---------------------------------------------------------------------------
__global__ __launch_bounds__(256) void nca_flash_mfma(
    const unsigned short* __restrict__ emb, const float* __restrict__ nrm,
    const float* __restrict__ y, float* __restrict__ gl, float* __restrict__ gy,
    int N, int jspan)
{
    __shared__ __align__(16) unsigned short hA[8192];  // 4 rc x 4 kc chunks
    __shared__ __align__(16) unsigned short sB[8192];
    __shared__ float h2s[64], s2s[64], ys[64];

    const int t = threadIdx.x, wave = t >> 6, lane = t & 63;
    const int quad = lane >> 4, lq = lane & 15;
    const int rsub = lane >> 2, kc8 = (lane & 3) * 8;
    const int i0 = blockIdx.x * 64;
    const int j0base = blockIdx.y * jspan;
    const int jend = min(j0base + jspan, N);
    const unsigned short* hb = emb + (size_t)N * 128;

    #pragma unroll
    for (int q = 0; q < 4; ++q)
        async16(hA + (wave * 4 + q) * 512,
                hb + (size_t)(i0 + wave * 16 + rsub) * 128 + q * 32 + kc8);
    if (t < 64) h2s[t] = nrm[N + i0 + t];
    __syncthreads();

    float myh2[4];
    #pragma unroll
    for (int r = 0; r < 4; ++r) myh2[r] = h2s[wave * 16 + quad * 4 + r];

    float lacc[4] = {0.f, 0.f, 0.f, 0.f};
    float yacc[4] = {0.f, 0.f, 0.f, 0.f};

    for (int j0 = j0base; j0 < jend; j0 += 64) {
        __syncthreads();
        int jr = min(j0 + wave * 16 + rsub, jend - 1);
        #pragma unroll
        for (int q = 0; q < 4; ++q)
            async16(sB + (wave * 4 + q) * 512,
                    emb + (size_t)jr * 128 + q * 32 + kc8);
        if (t < 64) {
            int j = j0 + t;
            s2s[t] = (j < jend) ? nrm[j] : 1e30f;
            ys[t]  = (j < jend) ? y[j] : 0.f;
        }
        __syncthreads();

        f32x4 acc[4];
        #pragma unroll
        for (int jt = 0; jt < 4; ++jt) acc[jt] = (f32x4){0.f, 0.f, 0.f, 0.f};
        #pragma unroll
        for (int kk = 0; kk < 4; ++kk) {
            bf16x8 a = *(const bf16x8*)&hA[(wave * 4 + kk) * 512 + lq * 32 + quad * 8];
            #pragma unroll
            for (int jt = 0; jt < 4; ++jt) {
                bf16x8 b = *(const bf16x8*)&sB[(jt * 4 + kk) * 512 + lq * 32 + quad * 8];
                acc[jt] = __builtin_amdgcn_mfma_f32_16x16x32_bf16(a, b, acc[jt], 0, 0, 0);
            }
        }

        #pragma unroll
        for (int jt = 0; jt < 4; ++jt) {
            int col = jt * 16 + lq;
            float ss = s2s[col];
            float sy = ys[col];
            #pragma unroll
            for (int r = 0; r < 4; ++r) {
                float d2 = myh2[r] + ss - 2.f * acc[jt][r];
                float d  = sqrtf(fmaxf(d2, 0.f) + EPSF);
                float p  = __expf(-d);
                lacc[r] += p;
                yacc[r]  = fmaf(p, sy, yacc[r]);
            }
        }
    }

    #pragma unroll
    for (int r = 0; r < 4; ++r) {
        #pragma unroll
        for (int off = 8; off > 0; off >>= 1) {
            lacc[r] += __shfl_down(lacc[r], off, 16);
            yacc[r] += __shfl_down(yacc[r], off, 16);
        }
    }
    if (lq == 0) {
        int rowl = wave * 16 + quad * 4;
        #pragma unroll
        for (int r = 0; r < 4; ++r) {
            atomicAdd(&gl[i0 + rowl + r], lacc[r]);
            atomicAdd(&gy[i0 + rowl + r], yacc[r]);
        }
    }
}

__global__ __launch_bounds__(256) void finalize_div(
    const float* __restrict__ gl, const float* __restrict__ gy,
    float* __restrict__ out, int B)
{
    int i = blockIdx.x * 256 + threadIdx.x;
    if (i < B) out[i] = gy[i] / gl[i];
}

// ---------------------------------------------------------------------------
extern "C" void kernel_launch(void* const* d_in, const int* in_sizes, int n_in,
                              void* d_out, int out_size, void* d_ws, size_t ws_size,
                              hipStream_t stream)
{
    const float* x    = (const float*)d_in[0];  // [1024,256]
    const float* subx = (const float*)d_in[1];  // [30000,256]
    const float* suby = (const float*)d_in[2];  // [30000]
    const float* W1   = (const float*)d_in[3];  // [256,512]
    const float* b1   = (const float*)d_in[4];  // [512]
    const float* W2   = (const float*)d_in[5];  // [512,128]
    const float* b2   = (const float*)d_in[6];  // [128]
    float* out = (float*)d_out;                 // [1024]

    const int B = 1024, N = 30000, D = 256, H1 = 512, H2 = 128;
    const int M = N + B;  // 31024 combined rows

    char* wsb = (char*)d_ws;
    size_t off = 0;
    auto alloc = [&](size_t bytes) -> char* {
        char* p = wsb + off;
        off += (bytes + 255) & ~(size_t)255;
        return p;
    };
    unsigned short* cxh  = (unsigned short*)alloc((size_t)M * D * 2);    // 15.9 MB
    unsigned short* cxl  = (unsigned short*)alloc((size_t)M * D * 2);
    unsigned short* w1hT = (unsigned short*)alloc((size_t)H1 * D * 2);
    unsigned short* w1lT = (unsigned short*)alloc((size_t)H1 * D * 2);
    unsigned short* w2hT = (unsigned short*)alloc((size_t)H2 * H1 * 2);
    unsigned short* w2lT = (unsigned short*)alloc((size_t)H2 * H1 * 2);
    unsigned short* z1   = (unsigned short*)alloc((size_t)M * H1 * 2);   // 31.8 MB
    unsigned short* emb  = (unsigned short*)alloc((size_t)M * H2 * 2);   // 7.9 MB
    float* nrm = (float*)alloc((size_t)M * 4);
    float* gl  = (float*)alloc((size_t)B * 4);
    float* gy  = (float*)alloc((size_t)B * 4);
    (void)ws_size; (void)in_sizes; (void)n_in; (void)out_size;

    dim3 blk(256);
    // prep: combined split (+ gl/gy zeroing), weight transpose-splits
    split_combined<<<dim3(M * D / 4 / 256), blk, 0, stream>>>(
        subx, x, cxh, cxl, gl, gy, M * D / 4, N);
    tsplit<<<dim3(D * H1 / 256), blk, 0, stream>>>(W1, w1hT, w1lT, 8, H1, D * H1);
    tsplit<<<dim3(H1 * H2 / 256), blk, 0, stream>>>(W2, w2hT, w2lT, 9, H2, H1 * H2);
    // layer 1 (3-term), 1D grid with XCD swizzle: 243 m-tiles x 4 n-tiles
    gemm_l1<<<dim3(((M + 127) / 128) * (H1 / 128)), blk, 0, stream>>>(
        cxh, cxl, w1hT, w1lT, b1, z1, M, D, H1);
    // layer 2 (2-term) + rounded-row norms
    gemm_l2_norm<<<dim3((M + 127) / 128), blk, 0, stream>>>(
        z1, w2hT, w2lT, b2, emb, nrm, M, H1);
    // pairwise + softmax-weighted sum
    const int JSPAN = 512;
    const int NSPLIT = (N + JSPAN - 1) / JSPAN;  // 59
    nca_flash_mfma<<<dim3(B / 64, NSPLIT), blk, 0, stream>>>(
        emb, nrm, suby, gl, gy, N, JSPAN);
    finalize_div<<<dim3(B / 256), blk, 0, stream>>>(gl, gy, out, B);
}